// Round 8
// baseline (613.038 us; speedup 1.0000x reference)
//
#include <hip/hip_runtime.h>
#include <hip/hip_bf16.h>
#include <stdint.h>

#define TSEQ   2048
#define DMODEL 6144
#define NHEADS 48
#define NKVH   8
#define HDIM   128
#define QKVC   8192   // (48 + 2*8) * 128
#define GRP    6      // NHEADS / NKVH

typedef __attribute__((ext_vector_type(8))) short short8;
typedef __attribute__((ext_vector_type(4))) float f32x4;
typedef __attribute__((ext_vector_type(16))) float f32x16;

// ---------- helpers ----------

__device__ __forceinline__ unsigned short f2b(float f) {
  union { float f; unsigned int u; } v; v.f = f;
  unsigned int u = v.u;
  unsigned int r = (u + 0x7FFFu + ((u >> 16) & 1u)) >> 16;  // RNE
  return (unsigned short)r;
}

#if __has_builtin(__builtin_amdgcn_exp2f)
#define EXP2(x) __builtin_amdgcn_exp2f(x)
#else
#define EXP2(x) exp2f(x)
#endif
#if __has_builtin(__builtin_amdgcn_rcpf)
#define RCP(x) __builtin_amdgcn_rcpf(x)
#else
#define RCP(x) (1.0f / (x))
#endif

typedef const __attribute__((address_space(1))) void* as1_cvp;
typedef __attribute__((address_space(3))) void* as3_vp;

__device__ __forceinline__ void gload_lds16(const void* g, void* l) {
  // LDS dest is wave-uniform base + lane*16 (layouts below are linear in tid)
  __builtin_amdgcn_global_load_lds(
      (as1_cvp)(uintptr_t)g,
      (as3_vp)(unsigned int)(uintptr_t)l, 16, 0, 0);
}

#define LGKMC(n) do { asm volatile("s_waitcnt lgkmcnt(" #n ")" ::: "memory"); \
                      __builtin_amdgcn_sched_barrier(0); } while (0)
#define VMC(n) do { asm volatile("s_waitcnt vmcnt(" #n ")" ::: "memory"); \
                    __builtin_amdgcn_sched_barrier(0); } while (0)
#define BARR  do { asm volatile("s_barrier" ::: "memory"); } while (0)

// ---------- prep kernels ----------

__global__ __launch_bounds__(256) void k_cvt(const float* __restrict__ in,
                                             unsigned short* __restrict__ outp, int n) {
  int i = (blockIdx.x * 256 + threadIdx.x) * 8;
  if (i + 7 < n) {
    float4 va = *(const float4*)(in + i);
    float4 vb = *(const float4*)(in + i + 4);
    union { unsigned short s[8]; uint4 u; } o;
    o.s[0] = f2b(va.x); o.s[1] = f2b(va.y); o.s[2] = f2b(va.z); o.s[3] = f2b(va.w);
    o.s[4] = f2b(vb.x); o.s[5] = f2b(vb.y); o.s[6] = f2b(vb.z); o.s[7] = f2b(vb.w);
    *(uint4*)(outp + i) = o.u;
  }
}

// generic f32 -> bf16 64x64 tile transpose: out[c][r] = in[r][c]
__global__ __launch_bounds__(256) void k_tr2(const float* __restrict__ in, long istr, long zin,
                                             unsigned short* __restrict__ out, long ostr, long zout) {
  __shared__ unsigned short tile[64][68];
  const int tid = threadIdx.x;
  const int br = blockIdx.y * 64;      // input row base
  const int bc = blockIdx.x * 64;      // input col base
  in  += (size_t)blockIdx.z * zin;
  out += (size_t)blockIdx.z * zout;
  const int row = tid >> 4;            // 0..15
  const int c4  = (tid & 15) * 4;
#pragma unroll
  for (int p = 0; p < 4; ++p) {
    const int r = p * 16 + row;
    float4 v = *(const float4*)(in + (size_t)(br + r) * istr + bc + c4);
    tile[r][c4 + 0] = f2b(v.x);
    tile[r][c4 + 1] = f2b(v.y);
    tile[r][c4 + 2] = f2b(v.z);
    tile[r][c4 + 3] = f2b(v.w);
  }
  __syncthreads();
#pragma unroll
  for (int p = 0; p < 4; ++p) {
    const int r = p * 16 + row;        // out row (= input col index)
    union { unsigned short s[4]; uint2 u; } o;
    o.s[0] = tile[c4 + 0][r];
    o.s[1] = tile[c4 + 1][r];
    o.s[2] = tile[c4 + 2][r];
    o.s[3] = tile[c4 + 3][r];
    *(uint2*)(out + (size_t)(bc + r) * ostr + br + c4) = o.u;
  }
}

__global__ void k_trig(const int* __restrict__ pos, float* __restrict__ cs,
                       float* __restrict__ sn) {
  int t = blockIdx.x, i = threadIdx.x;  // block=64
  float p = (float)pos[t];
  float inv = EXP2(-(float)(2 * i) * (1.0f / 128.0f) * 13.287712379549449f);
  float f = p * inv;
  cs[t * 64 + i] = cosf(f);
  sn[t * 64 + i] = sinf(f);
}

// ---------- GEMM 256x256x64: round-5 schedule (best verified) + 32x32x16 MFMA ----------
// A[M][K] bf16 row-major, Bt[N][K] bf16, C[M][N] f32.
// 512 thr = 8 waves (2M x 4N); per-wave out 128x64 = 2mh x 2mt x 2nh tiles of
// 32x32, acc = f32x16 [2][2][2] (128 VGPR).
// LDS (dynamic 128 KiB): buf b at b*65536: A 256 rows x 128 B (XOR-swizzled
// byte^=(row&7)<<4), B at +32768 same. All row bases are multiples of 32 so
// row&7 == lane&7 (lsw) for every fragment read.
// Schedule per tile t (buf cur=t&1): issue ALL 24 ds_reads up-front
// (a0 8 | b0 4 | STAGE_B(t+1) | b1 4 | a1 8), consume with counted lgkmcnt;
// 2 barriers/tile:
//   lgkm(12) MFMA(0,*,0); lgkm(8) MFMA(0,*,1); lgkm(0) MFMA(1,*,0);
//   BARR; STAGE_A(t+2,cur); MFMA(1,*,1); vmcnt(4); BARR
// Ledger: vmcnt(4) leaves A(t+2) in flight; A(t+1), B(t+1) landed. lgkm(0)
// precedes mid-BARR in program order so all reads of buf cur drained before
// STAGE_A overwrites it. B(t+1) writes buf cur^1 whose readers finished >=2
// barriers earlier.
// 32x32x16 frags: A row = lane&31, k = kstep*16 + (lane>>5)*8 + [0..7]
//   -> byte = row*128 + ((ks*32 + (lane>>5)*16) ^ lsw). B symmetric on Bt.
// C/D (m74/m101): col = lane&31, row = (reg&3) + 8*(reg>>2) + 4*(lane>>5).

#define READ_A32(mh, aa) do { \
  _Pragma("unroll") for (int mt = 0; mt < 2; ++mt) \
  _Pragma("unroll") for (int ks = 0; ks < 4; ++ks) \
    aa[mt][ks] = *(const short8*)(LA + (wm * 128 + (mh) * 64 + mt * 32 + l32) * 128 \
                                  + ((ks * 32 + kh16) ^ lsw)); } while (0)

#define READ_B32(nh, bb) do { \
  _Pragma("unroll") for (int ks = 0; ks < 4; ++ks) \
    bb[ks] = *(const short8*)(LB + (wn * 64 + (nh) * 32 + l32) * 128 \
                              + ((ks * 32 + kh16) ^ lsw)); } while (0)

#define CLUSTER32(mh, nh, aa, bb) do { \
  __builtin_amdgcn_s_setprio(1); \
  _Pragma("unroll") for (int mt = 0; mt < 2; ++mt) \
  _Pragma("unroll") for (int ks = 0; ks < 4; ++ks) \
    acc[mh][mt][nh] = __builtin_amdgcn_mfma_f32_32x32x16_bf16( \
        aa[mt][ks], bb[ks], acc[mh][mt][nh], 0, 0, 0); \
  __builtin_amdgcn_s_setprio(0); } while (0)

#define STAGE_A(kt, bb) do { \
  _Pragma("unroll") for (int i = 0; i < 4; ++i) \
    gload_lds16(Asrc + (size_t)(kt) * 64 + (size_t)i * 64 * K, \
                lds + (bb) * 65536 + F + i * 8192); } while (0)

#define STAGE_B(kt, bb) do { \
  _Pragma("unroll") for (int i = 0; i < 4; ++i) \
    gload_lds16(Bsrc + (size_t)(kt) * 64 + (size_t)i * 64 * K, \
                lds + (bb) * 65536 + 32768 + F + i * 8192); } while (0)

__global__ __launch_bounds__(512, 2) void k_gemm8(const unsigned short* __restrict__ A,
                                                  const unsigned short* __restrict__ Bt,
                                                  float* __restrict__ C,
                                                  int M, int N, int K) {
  extern __shared__ __align__(16) unsigned char lds[];
  const int tid  = threadIdx.x;
  const int lane = tid & 63;
  const int wave = tid >> 6;
  const int wm = wave >> 2;           // 0..1
  const int wn = wave & 3;            // 0..3
  const int l32  = lane & 31;
  const int kh16 = (lane >> 5) * 16;  // k-half byte offset
  const int lsw  = (lane & 7) << 4;   // swizzle const (row&7 == lane&7 here)

  // XCD n-stripe mapping: xcd = lin&7 owns n-cols [xcd*Cx, (xcd+1)*Cx)
  const int mt_ = M >> 8;
  const int nt_ = N >> 8;
  const int Cx = nt_ >> 3;
  const int lin = blockIdx.x;
  const int xcd = lin & 7;
  const int r   = lin >> 3;
  const int m0  = (r % mt_) << 8;
  const int n0  = (xcd * Cx + r / mt_) << 8;

  // staging: thread's 16B chunk; row advances 64 per load index
  const int F   = tid * 16;
  const int r0  = F >> 7;
  const int cbs = (F & 127) ^ ((r0 & 7) << 4);   // pre-swizzled source col
  const unsigned short* Asrc = A  + (size_t)(m0 + r0) * K + (cbs >> 1);
  const unsigned short* Bsrc = Bt + (size_t)(n0 + r0) * K + (cbs >> 1);

  const int NT = K >> 6;

  f32x16 acc[2][2][2];
#pragma unroll
  for (int i = 0; i < 2; ++i)
#pragma unroll
    for (int j = 0; j < 2; ++j)
#pragma unroll
      for (int k = 0; k < 2; ++k)
#pragma unroll
        for (int e = 0; e < 16; ++e) acc[i][j][k][e] = 0.f;

  // prologue: A(0),B(0)->buf0, A(1)->buf1; wait first 8, keep A(1) flying
  STAGE_A(0, 0);
  STAGE_B(0, 0);
  STAGE_A(1, 1);
  VMC(4);
  BARR;

  for (int t = 0; t < NT; ++t) {
    const int cur = t & 1;
    const unsigned char* LA = lds + cur * 65536;
    const unsigned char* LB = LA + 32768;
    short8 a0[2][4], a1[2][4], b0[4], b1[4];

    // issue all reads up-front; stage B(t+1) interleaved
    READ_A32(0, a0);                     // 8  (lgkm 8)
    READ_B32(0, b0);                     // 4  (lgkm 12)
    if (t + 1 < NT) STAGE_B(t + 1, cur ^ 1);
    READ_B32(1, b1);                     // 4  (lgkm 16)
    READ_A32(1, a1);                     // 8  (lgkm 24)

    LGKMC(12);                           // a0,b0 landed
    CLUSTER32(0, 0, a0, b0);
    LGKMC(8);                            // b1 landed
    CLUSTER32(0, 1, a0, b1);
    LGKMC(0);                            // a1 landed (all reads drained)
    CLUSTER32(1, 0, a1, b0);
    BARR;                                // all waves drained -> safe to overwrite A(cur)
    if (t + 2 < NT) STAGE_A(t + 2, cur);
    CLUSTER32(1, 1, a1, b1);             // register-only, overlaps stage
    if (t + 2 < NT) { VMC(4); } else { VMC(0); }
    BARR;
  }

#pragma unroll
  for (int mh = 0; mh < 2; ++mh)
#pragma unroll
    for (int mt2 = 0; mt2 < 2; ++mt2)
#pragma unroll
      for (int nh = 0; nh < 2; ++nh)
#pragma unroll
        for (int reg = 0; reg < 16; ++reg) {
          int row = m0 + wm * 128 + mh * 64 + mt2 * 32 +
                    (reg & 3) + 8 * (reg >> 2) + 4 * (lane >> 5);
          int col = n0 + wn * 64 + nh * 32 + l32;
          C[(size_t)row * N + col] = acc[mh][mt2][nh][reg];
        }
}

// ---------- RoPE + split: QKV f32 [T][8192] -> Q[h][t][d], K[h][t][d] (bf16), vectorized ----------

__global__ __launch_bounds__(256) void k_rope(const float* __restrict__ qkv,
                                              const float* __restrict__ cs,
                                              const float* __restrict__ sn,
                                              unsigned short* __restrict__ Q,
                                              unsigned short* __restrict__ K) {
  const int t = blockIdx.x;
  const int tid = threadIdx.x;
  const float* row = qkv + (size_t)t * QKVC;
  const float* c = cs + t * 64;
  const float* s = sn + t * 64;
  for (int p = tid; p < 56 * 16; p += 256) {
    const int h = p >> 4, q4 = (p & 15) * 4;
    const float* src = row + h * 128;
    float4 x1 = *(const float4*)(src + q4);
    float4 x2 = *(const float4*)(src + 64 + q4);
    float4 cc = *(const float4*)(c + q4);
    float4 ss = *(const float4*)(s + q4);
    unsigned short* dst = (h < NHEADS)
        ? Q + ((size_t)h * TSEQ + t) * HDIM
        : K + ((size_t)(h - NHEADS) * TSEQ + t) * HDIM;
    union { unsigned short sh[4]; uint2 u; } o1, o2;
    o1.sh[0] = f2b(x1.x * cc.x - x2.x * ss.x);
    o1.sh[1] = f2b(x1.y * cc.y - x2.y * ss.y);
    o1.sh[2] = f2b(x1.z * cc.z - x2.z * ss.z);
    o1.sh[3] = f2b(x1.w * cc.w - x2.w * ss.w);
    o2.sh[0] = f2b(x2.x * cc.x + x1.x * ss.x);
    o2.sh[1] = f2b(x2.y * cc.y + x1.y * ss.y);
    o2.sh[2] = f2b(x2.z * cc.z + x1.z * ss.z);
    o2.sh[3] = f2b(x2.w * cc.w + x1.w * ss.w);
    *(uint2*)(dst + q4) = o1.u;
    *(uint2*)(dst + 64 + q4) = o2.u;
  }
}

// ---------- attention (balanced pairs + LDS staging) ----------

__global__ __launch_bounds__(256, 3) void k_attn2(const unsigned short* __restrict__ Q,
                                                  const unsigned short* __restrict__ K,
                                                  const unsigned short* __restrict__ V,  // Vt[h][d][t]
                                                  unsigned short* __restrict__ O) {
  __shared__ __align__(16) unsigned char KsB[16384];      // 64 s-rows x 256 B (swizzled)
  __shared__ __align__(16) unsigned char VsB[16384];      // 128 d-rows x 128 B (swizzled)
  __shared__ __align__(16) unsigned char PsB[4][2048];    // per-wave 16 q-rows x 128 B (swizzled)

  const int lin = blockIdx.x;
  const int g   = lin & 7;            // kv head == XCD hint
  const int rr  = lin >> 3;           // 0..95
  const int hg  = rr % 6;
  const int pr  = rr / 6;             // 0..15
  const int h   = g * 6 + hg;
  const int tid = threadIdx.x, wave = tid >> 6, lane = tid & 63;
  const int lr = lane & 15, lk = (lane >> 4) * 8, li4 = (lane >> 4) * 4;
  const unsigned short* Qh = Q + (size_t)h * (TSEQ * HDIM);
  const unsigned char*  Kb = (const unsigned char*)(K + (size_t)g * (TSEQ * HDIM));
  const unsigned char*  Vb = (const unsigned char*)(V + (size_t)g * (TSEQ * HDIM));
  unsigned char* Pw = PsB[wave];

  for (int half = 0; half < 2; ++half) {
    const int j  = half ? (31 - pr) : pr;     // q-tile index (64 rows)
    const int t0 = j * 64 + wave * 16;        // this wave's 16 rows
    const int nst = j + 1;

    short8 qf[4];
#pragma unroll
    for (int ks = 0; ks < 4; ++ks)
      qf[ks] = *(const short8*)(Qh + (size_t)(t0 + lr) * HDIM + ks * 32 + lk);

    f32x4 oacc[8];
#pragma unroll
    for (int n = 0; n < 8; ++n) oacc[n] = (f32x4){0.f, 0.f, 0.f, 0.f};
    float rs4[4] = {0.f, 0.f, 0.f, 0.f};

    for (int st = 0; st < nst; ++st) {
      const int s0 = st * 64;
#pragma unroll
      for (int c = 0; c < 4; ++c) {
        const int FF = tid * 16 + c * 4096;
        const int krow = FF >> 8;
        const int kcol = (FF & 255) ^ ((krow & 7) << 4);
        gload_lds16(Kb + (size_t)(s0 + krow) * 256 + kcol, KsB + FF);
        const int vrow = FF >> 7;
        const int vcol = (FF & 127) ^ ((vrow & 7) << 4);
        gload_lds16(Vb + (size_t)vrow * (TSEQ * 2) + (size_t)s0 * 2 + vcol, VsB + FF);
      }
      __syncthreads();

      f32x4 sacc[4];
#pragma unroll
      for (int n = 0; n < 4; ++n) sacc[n] = (f32x4){0.f, 0.f, 0.f, 0.f};
#pragma unroll
      for (int ks = 0; ks < 4; ++ks) {
        short8 kf[4];
#pragma unroll
        for (int n = 0; n < 4; ++n) {
          const int row = n * 16 + lr;
          kf[n] = *(const short8*)(KsB + row * 256 + ((ks * 64 + lk * 2) ^ ((row & 7) << 4)));
        }
#pragma unroll
        for (int n = 0; n < 4; ++n)
          sacc[n] = __builtin_amdgcn_mfma_f32_16x16x32_bf16(qf[ks], kf[n], sacc[n], 0, 0, 0);
      }

      const bool lastst = (st == nst - 1);
#pragma unroll
      for (int n = 0; n < 4; ++n)
#pragma unroll
        for (int i = 0; i < 4; ++i) {
          float sv = sacc[n][i] * 0.08838834764831845f;   // 1/sqrt(128)
          float e = EXP2(sv * 0.09617966939259757f);       // e^(s/15)
          float p = EXP2(-86.5617024533378f * RCP(e + 1.0f));
          if (lastst && (s0 + n * 16 + lr > t0 + li4 + i)) p = 0.f;
          rs4[i] += p;
          const int prow = li4 + i;
          *(unsigned short*)(Pw + prow * 128 +
              (((n * 16 + lr) * 2) ^ ((prow & 7) << 4))) = f2b(p);
        }

#pragma unroll
      for (int ks2 = 0; ks2 < 2; ++ks2) {
        short8 pf = *(const short8*)(Pw + lr * 128 +
                         (((ks2 * 32 + lk) * 2) ^ ((lr & 7) << 4)));
        short8 vf[8];
#pragma unroll
        for (int n = 0; n < 8; ++n) {
          const int row = n * 16 + lr;
          vf[n] = *(const short8*)(VsB + row * 128 + ((ks2 * 64 + lk * 2) ^ ((row & 7) << 4)));
        }
#pragma unroll
        for (int n = 0; n < 8; ++n)
          oacc[n] = __builtin_amdgcn_mfma_f32_16x16x32_bf16(pf, vf[n], oacc[n], 0, 0, 0);
      }
      __syncthreads();
    }

    float inv4[4];
#pragma unroll
    for (int i = 0; i < 4; ++i) {
      float v = rs4[i];
      v += __shfl_xor(v, 1, 64);
      v += __shfl_xor(v, 2, 64);
      v += __shfl_xor(v, 4, 64);
      v += __shfl_xor(v, 8, 64);
      inv4[i] = RCP(v);
    }
#pragma unroll
    for (int n = 0; n < 8; ++n)
#pragma unroll
      for (int i = 0; i < 4; ++i)
        O[(size_t)(t0 + li4 + i) * DMODEL + h * HDIM + n * 16 + lr] =
            f2b(oacc[n][i] * inv4[i]);
  }
}

// ---------- launch ----------

extern "C" void kernel_launch(void* const* d_in, const int* in_sizes, int n_in,
                              void* d_out, int out_size, void* d_ws, size_t ws_size,
                              hipStream_t stream) {
  const int*   pos  = (const int*)d_in[0];
  const float* hid  = (const float*)d_in[1];
  const float* wqkv = (const float*)d_in[2];
  const float* wo   = (const float*)d_in[3];
  float* out = (float*)d_out;
  char* ws = (char*)d_ws;

  const size_t O_XB   = 0;                         // Xb bf16 [2048][6144]; later attn_out
  const size_t O_WQT  = 25165824;                  // Wqkv^T bf16 [8192][6144]; later Q/K/Vt
  const size_t O_WOT  = 125829120;                 // Wo^T bf16 [6144][6144]
  const size_t O_QKV  = 201326592;                 // QKV f32 [2048][8192]
  const size_t O_TRIG = 268435456;                 // cos/sin f32 [2048][64] each

  unsigned short* Xb  = (unsigned short*)(ws + O_XB);
  unsigned short* Wqt = (unsigned short*)(ws + O_WQT);
  unsigned short* Wot = (unsigned short*)(ws + O_WOT);
  float* QKV = (float*)(ws + O_QKV);
  float* CS  = (float*)(ws + O_TRIG);
  float* SN  = CS + TSEQ * 64;
  unsigned short* Qr = Wqt;                                  // [48][2048][128]
  unsigned short* Kr = Wqt + (size_t)NHEADS * TSEQ * HDIM;   // [8][2048][128]
  unsigned short* Vt = Kr + (size_t)NKVH * TSEQ * HDIM;      // [8][128][2048]
  unsigned short* AO = Xb;                                   // attn_out bf16 [2048][6144]

  hipFuncSetAttribute((const void*)k_gemm8,
                      hipFuncAttributeMaxDynamicSharedMemorySize, 131072);

  k_cvt<<<(TSEQ * DMODEL) / (256 * 8), 256, 0, stream>>>(hid, Xb, TSEQ * DMODEL);
  // Wqkv^T: in 6144x8192 -> out 8192x6144
  k_tr2<<<dim3(QKVC / 64, DMODEL / 64, 1), 256, 0, stream>>>(wqkv, QKVC, 0, Wqt, DMODEL, 0);
  // Wo^T: in 6144x6144 -> out 6144x6144
  k_tr2<<<dim3(DMODEL / 64, DMODEL / 64, 1), 256, 0, stream>>>(wo, DMODEL, 0, Wot, DMODEL, 0);
  k_trig<<<TSEQ, 64, 0, stream>>>(pos, CS, SN);

  k_gemm8<<<(TSEQ / 256) * (QKVC / 256), 512, 131072, stream>>>(Xb, Wqt, QKV,
                                                                TSEQ, QKVC, DMODEL);
  k_rope<<<TSEQ, 256, 0, stream>>>(QKV, CS, SN, Qr, Kr);
  // Vt: per head z, in QKV[t][7168 + z*128 + d] (2048x128) -> Vt[z][d][t]
  k_tr2<<<dim3(HDIM / 64, TSEQ / 64, NKVH), 256, 0, stream>>>(
      QKV + (size_t)(DMODEL + NKVH * HDIM), QKVC, HDIM,
      Vt, TSEQ, (size_t)HDIM * TSEQ);
  k_attn2<<<768, 256, 0, stream>>>(Qr, Kr, Vt, AO);
  k_gemm8<<<(TSEQ / 256) * (DMODEL / 256), 512, 131072, stream>>>(AO, Wot, out,
                                                                  TSEQ, DMODEL, DMODEL);
}

// Round 9
// 539.900 us; speedup vs baseline: 1.1355x; 1.1355x over previous
//
#include <hip/hip_runtime.h>
#include <hip/hip_bf16.h>
#include <stdint.h>

#define TSEQ   2048
#define DMODEL 6144
#define NHEADS 48
#define NKVH   8
#define HDIM   128
#define QKVC   8192   // (48 + 2*8) * 128
#define GRP    6      // NHEADS / NKVH

typedef __attribute__((ext_vector_type(8))) short short8;
typedef __attribute__((ext_vector_type(4))) float f32x4;

// ---------- helpers ----------

__device__ __forceinline__ unsigned short f2b(float f) {
  union { float f; unsigned int u; } v; v.f = f;
  unsigned int u = v.u;
  unsigned int r = (u + 0x7FFFu + ((u >> 16) & 1u)) >> 16;  // RNE
  return (unsigned short)r;
}

__device__ __forceinline__ float b2f(unsigned short s) {
  union { unsigned int u; float f; } v; v.u = ((unsigned int)s) << 16;
  return v.f;
}

#if __has_builtin(__builtin_amdgcn_exp2f)
#define EXP2(x) __builtin_amdgcn_exp2f(x)
#else
#define EXP2(x) exp2f(x)
#endif
#if __has_builtin(__builtin_amdgcn_rcpf)
#define RCP(x) __builtin_amdgcn_rcpf(x)
#else
#define RCP(x) (1.0f / (x))
#endif

typedef const __attribute__((address_space(1))) void* as1_cvp;
typedef __attribute__((address_space(3))) void* as3_vp;

__device__ __forceinline__ void gload_lds16(const void* g, void* l) {
  // LDS dest is wave-uniform base + lane*16 (layouts below are linear in tid)
  __builtin_amdgcn_global_load_lds(
      (as1_cvp)(uintptr_t)g,
      (as3_vp)(unsigned int)(uintptr_t)l, 16, 0, 0);
}

#define LGKMC(n) do { asm volatile("s_waitcnt lgkmcnt(" #n ")" ::: "memory"); \
                      __builtin_amdgcn_sched_barrier(0); } while (0)
#define VMC(n) do { asm volatile("s_waitcnt vmcnt(" #n ")" ::: "memory"); \
                    __builtin_amdgcn_sched_barrier(0); } while (0)
#define BARR  do { asm volatile("s_barrier" ::: "memory"); } while (0)

// ---------- prep kernels ----------

__global__ __launch_bounds__(256) void k_cvt(const float* __restrict__ in,
                                             unsigned short* __restrict__ outp, int n) {
  int i = (blockIdx.x * 256 + threadIdx.x) * 8;
  if (i + 7 < n) {
    float4 va = *(const float4*)(in + i);
    float4 vb = *(const float4*)(in + i + 4);
    union { unsigned short s[8]; uint4 u; } o;
    o.s[0] = f2b(va.x); o.s[1] = f2b(va.y); o.s[2] = f2b(va.z); o.s[3] = f2b(va.w);
    o.s[4] = f2b(vb.x); o.s[5] = f2b(vb.y); o.s[6] = f2b(vb.z); o.s[7] = f2b(vb.w);
    *(uint4*)(outp + i) = o.u;
  }
}

// f32 -> bf16 64x64 tile transpose: out[c][r] = in[r][c]
__global__ __launch_bounds__(256) void k_tr2(const float* __restrict__ in, long istr, long zin,
                                             unsigned short* __restrict__ out, long ostr, long zout) {
  __shared__ unsigned short tile[64][68];
  const int tid = threadIdx.x;
  const int br = blockIdx.y * 64;      // input row base
  const int bc = blockIdx.x * 64;      // input col base
  in  += (size_t)blockIdx.z * zin;
  out += (size_t)blockIdx.z * zout;
  const int row = tid >> 4;            // 0..15
  const int c4  = (tid & 15) * 4;
#pragma unroll
  for (int p = 0; p < 4; ++p) {
    const int r = p * 16 + row;
    float4 v = *(const float4*)(in + (size_t)(br + r) * istr + bc + c4);
    tile[r][c4 + 0] = f2b(v.x);
    tile[r][c4 + 1] = f2b(v.y);
    tile[r][c4 + 2] = f2b(v.z);
    tile[r][c4 + 3] = f2b(v.w);
  }
  __syncthreads();
#pragma unroll
  for (int p = 0; p < 4; ++p) {
    const int r = p * 16 + row;        // out row (= input col index)
    union { unsigned short s[4]; uint2 u; } o;
    o.s[0] = tile[c4 + 0][r];
    o.s[1] = tile[c4 + 1][r];
    o.s[2] = tile[c4 + 2][r];
    o.s[3] = tile[c4 + 3][r];
    *(uint2*)(out + (size_t)(bc + r) * ostr + br + c4) = o.u;
  }
}

// bf16 -> bf16 64x64 tile transpose: out[c][r] = in[r][c]
__global__ __launch_bounds__(256) void k_tr2b(const unsigned short* __restrict__ in, long istr, long zin,
                                              unsigned short* __restrict__ out, long ostr, long zout) {
  __shared__ unsigned short tile[64][68];
  const int tid = threadIdx.x;
  const int br = blockIdx.y * 64;
  const int bc = blockIdx.x * 64;
  in  += (size_t)blockIdx.z * zin;
  out += (size_t)blockIdx.z * zout;
  const int row = tid >> 4;            // 0..15
  const int c4  = (tid & 15) * 4;
#pragma unroll
  for (int p = 0; p < 4; ++p) {
    const int r = p * 16 + row;
    union { unsigned short s[4]; uint2 u; } v;
    v.u = *(const uint2*)(in + (size_t)(br + r) * istr + bc + c4);
    tile[r][c4 + 0] = v.s[0];
    tile[r][c4 + 1] = v.s[1];
    tile[r][c4 + 2] = v.s[2];
    tile[r][c4 + 3] = v.s[3];
  }
  __syncthreads();
#pragma unroll
  for (int p = 0; p < 4; ++p) {
    const int r = p * 16 + row;
    union { unsigned short s[4]; uint2 u; } o;
    o.s[0] = tile[c4 + 0][r];
    o.s[1] = tile[c4 + 1][r];
    o.s[2] = tile[c4 + 2][r];
    o.s[3] = tile[c4 + 3][r];
    *(uint2*)(out + (size_t)(bc + r) * ostr + br + c4) = o.u;
  }
}

__global__ void k_trig(const int* __restrict__ pos, float* __restrict__ cs,
                       float* __restrict__ sn) {
  int t = blockIdx.x, i = threadIdx.x;  // block=64
  float p = (float)pos[t];
  float inv = EXP2(-(float)(2 * i) * (1.0f / 128.0f) * 13.287712379549449f);
  float f = p * inv;
  cs[t * 64 + i] = cosf(f);
  sn[t * 64 + i] = sinf(f);
}

// ---------- GEMM 256x256x64: round-5 schedule (best verified), templated out dtype ----------
// A[M][K] bf16 row-major, Bt[N][K] bf16, C[M][N] f32 or bf16.
// 512 thr = 8 waves (2M x 4N); per-wave out 128x64 = acc[4][4] f32x4 x 4.
// LDS (dynamic 128 KiB): buf b at b*65536: A 256 rows x 128 B (XOR-swizzled
// byte^=(row&7)<<4), B at +32768 same.
// Per tile t (buf cur=t&1): issue ALL 24 ds_reads up-front (a0,b0 | b1 | a1),
// STAGE_B(t+1) interleaved; consume with counted lgkmcnt; 2 barriers/tile:
//   lgkm(12) MFMA(0,0); lgkm(8) MFMA(0,1); lgkm(0) MFMA(1,0);
//   BARR; STAGE_A(t+2,cur); MFMA(1,1); vmcnt(4); BARR
// Ledger: vmcnt(4) leaves A(t+2) in flight; A(t+1), B(t+1) landed. lgkm(0)
// precedes mid-BARR so all reads of buf cur drain before STAGE_A overwrites.

#define READ_A(mh, aa) do { \
  _Pragma("unroll") for (int m = 0; m < 4; ++m) \
  _Pragma("unroll") for (int ks = 0; ks < 2; ++ks) \
    aa[m][ks] = *(const short8*)(LA + (wm * 128 + (mh) * 64 + m * 16 + lr) * 128 \
                                 + ((ks * 64 + lkb) ^ lsw)); } while (0)

#define READ_B(nh, bb) do { \
  _Pragma("unroll") for (int n2 = 0; n2 < 2; ++n2) \
  _Pragma("unroll") for (int ks = 0; ks < 2; ++ks) \
    bb[n2][ks] = *(const short8*)(LB + (wn * 64 + (nh) * 32 + n2 * 16 + lr) * 128 \
                                  + ((ks * 64 + lkb) ^ lsw)); } while (0)

#define CLUSTER(mh, nh, aa, bb) do { \
  __builtin_amdgcn_s_setprio(1); \
  _Pragma("unroll") for (int m = 0; m < 4; ++m) \
  _Pragma("unroll") for (int n2 = 0; n2 < 2; ++n2) \
  _Pragma("unroll") for (int ks = 0; ks < 2; ++ks) \
    acc[(mh) * 4 + m][(nh) * 2 + n2] = __builtin_amdgcn_mfma_f32_16x16x32_bf16( \
        aa[m][ks], bb[n2][ks], acc[(mh) * 4 + m][(nh) * 2 + n2], 0, 0, 0); \
  __builtin_amdgcn_s_setprio(0); } while (0)

#define STAGE_A(kt, bb) do { \
  _Pragma("unroll") for (int i = 0; i < 4; ++i) \
    gload_lds16(Asrc + (size_t)(kt) * 64 + (size_t)i * 64 * K, \
                lds + (bb) * 65536 + F + i * 8192); } while (0)

#define STAGE_B(kt, bb) do { \
  _Pragma("unroll") for (int i = 0; i < 4; ++i) \
    gload_lds16(Bsrc + (size_t)(kt) * 64 + (size_t)i * 64 * K, \
                lds + (bb) * 65536 + 32768 + F + i * 8192); } while (0)

template <typename OutT>
__global__ __launch_bounds__(512, 2) void k_gemm8(const unsigned short* __restrict__ A,
                                                  const unsigned short* __restrict__ Bt,
                                                  OutT* __restrict__ C,
                                                  int M, int N, int K) {
  extern __shared__ __align__(16) unsigned char lds[];
  const int tid  = threadIdx.x;
  const int lane = tid & 63;
  const int wave = tid >> 6;
  const int wm = wave >> 2;           // 0..1
  const int wn = wave & 3;            // 0..3
  const int lr  = lane & 15;
  const int lkb = (lane >> 4) * 16;
  const int li4 = (lane >> 4) * 4;
  const int lsw = (lane & 7) << 4;    // read-side swizzle const

  // XCD n-stripe mapping: xcd = lin&7 owns n-cols [xcd*Cx, (xcd+1)*Cx)
  const int mt = M >> 8;
  const int nt = N >> 8;
  const int Cx = nt >> 3;
  const int lin = blockIdx.x;
  const int xcd = lin & 7;
  const int r   = lin >> 3;
  const int m0  = (r % mt) << 8;
  const int n0  = (xcd * Cx + r / mt) << 8;

  // staging: thread's 16B chunk; row advances 64 per load index
  const int F   = tid * 16;
  const int r0  = F >> 7;
  const int cbs = (F & 127) ^ ((r0 & 7) << 4);   // pre-swizzled source col
  const unsigned short* Asrc = A  + (size_t)(m0 + r0) * K + (cbs >> 1);
  const unsigned short* Bsrc = Bt + (size_t)(n0 + r0) * K + (cbs >> 1);

  const int NT = K >> 6;

  f32x4 acc[8][4];
#pragma unroll
  for (int i = 0; i < 8; ++i)
#pragma unroll
    for (int j = 0; j < 4; ++j) acc[i][j] = (f32x4){0.f, 0.f, 0.f, 0.f};

  // prologue: A(0),B(0)->buf0, A(1)->buf1; wait first 8, keep A(1) flying
  STAGE_A(0, 0);
  STAGE_B(0, 0);
  STAGE_A(1, 1);
  VMC(4);
  BARR;

  for (int t = 0; t < NT; ++t) {
    const int cur = t & 1;
    const unsigned char* LA = lds + cur * 65536;
    const unsigned char* LB = LA + 32768;
    short8 a0[4][2], a1[4][2], b0[2][2], b1[2][2];

    // issue all reads up-front; stage B(t+1) interleaved
    READ_A(0, a0);                       // 8  (lgkm 8)
    READ_B(0, b0);                       // 4  (lgkm 12)
    if (t + 1 < NT) STAGE_B(t + 1, cur ^ 1);
    READ_B(1, b1);                       // 4  (lgkm 16)
    READ_A(1, a1);                       // 8  (lgkm 24)

    LGKMC(12);                           // a0,b0 landed
    CLUSTER(0, 0, a0, b0);
    LGKMC(8);                            // b1 landed
    CLUSTER(0, 1, a0, b1);
    LGKMC(0);                            // a1 landed (all reads drained)
    CLUSTER(1, 0, a1, b0);
    BARR;                                // all waves drained -> safe to overwrite A(cur)
    if (t + 2 < NT) STAGE_A(t + 2, cur);
    CLUSTER(1, 1, a1, b1);               // register-only, overlaps stage
    if (t + 2 < NT) { VMC(4); } else { VMC(0); }
    BARR;
  }

#pragma unroll
  for (int mh = 0; mh < 2; ++mh)
#pragma unroll
    for (int m = 0; m < 4; ++m)
#pragma unroll
      for (int nh = 0; nh < 2; ++nh)
#pragma unroll
        for (int n2 = 0; n2 < 2; ++n2)
#pragma unroll
          for (int i = 0; i < 4; ++i) {
            int row = m0 + wm * 128 + mh * 64 + m * 16 + li4 + i;
            int col = n0 + wn * 64 + nh * 32 + n2 * 16 + lr;
            float v = acc[mh * 4 + m][nh * 2 + n2][i];
            if constexpr (sizeof(OutT) == 2)
              C[(size_t)row * N + col] = (OutT)f2b(v);
            else
              C[(size_t)row * N + col] = (OutT)v;
          }
}

// ---------- RoPE + split: QKV bf16 [T][8192] -> Q[h][t][d], K[h][t][d] (bf16) ----------

__global__ __launch_bounds__(256) void k_rope(const unsigned short* __restrict__ qkv,
                                              const float* __restrict__ cs,
                                              const float* __restrict__ sn,
                                              unsigned short* __restrict__ Q,
                                              unsigned short* __restrict__ K) {
  const int t = blockIdx.x;
  const int tid = threadIdx.x;
  const unsigned short* row = qkv + (size_t)t * QKVC;
  const float* c = cs + t * 64;
  const float* s = sn + t * 64;
  for (int p = tid; p < 56 * 16; p += 256) {
    const int h = p >> 4, q4 = (p & 15) * 4;
    const unsigned short* src = row + h * 128;
    union { unsigned short sh[4]; uint2 u; } x1u, x2u;
    x1u.u = *(const uint2*)(src + q4);
    x2u.u = *(const uint2*)(src + 64 + q4);
    float4 cc = *(const float4*)(c + q4);
    float4 ss = *(const float4*)(s + q4);
    unsigned short* dst = (h < NHEADS)
        ? Q + ((size_t)h * TSEQ + t) * HDIM
        : K + ((size_t)(h - NHEADS) * TSEQ + t) * HDIM;
    float x10 = b2f(x1u.sh[0]), x11 = b2f(x1u.sh[1]),
          x12 = b2f(x1u.sh[2]), x13 = b2f(x1u.sh[3]);
    float x20 = b2f(x2u.sh[0]), x21 = b2f(x2u.sh[1]),
          x22 = b2f(x2u.sh[2]), x23 = b2f(x2u.sh[3]);
    union { unsigned short sh[4]; uint2 u; } o1, o2;
    o1.sh[0] = f2b(x10 * cc.x - x20 * ss.x);
    o1.sh[1] = f2b(x11 * cc.y - x21 * ss.y);
    o1.sh[2] = f2b(x12 * cc.z - x22 * ss.z);
    o1.sh[3] = f2b(x13 * cc.w - x23 * ss.w);
    o2.sh[0] = f2b(x20 * cc.x + x10 * ss.x);
    o2.sh[1] = f2b(x21 * cc.y + x11 * ss.y);
    o2.sh[2] = f2b(x22 * cc.z + x12 * ss.z);
    o2.sh[3] = f2b(x23 * cc.w + x13 * ss.w);
    *(uint2*)(dst + q4) = o1.u;
    *(uint2*)(dst + 64 + q4) = o2.u;
  }
}

// ---------- attention (balanced pairs + LDS staging) ----------

__global__ __launch_bounds__(256, 3) void k_attn2(const unsigned short* __restrict__ Q,
                                                  const unsigned short* __restrict__ K,
                                                  const unsigned short* __restrict__ V,  // Vt[h][d][t]
                                                  unsigned short* __restrict__ O) {
  __shared__ __align__(16) unsigned char KsB[16384];      // 64 s-rows x 256 B (swizzled)
  __shared__ __align__(16) unsigned char VsB[16384];      // 128 d-rows x 128 B (swizzled)
  __shared__ __align__(16) unsigned char PsB[4][2048];    // per-wave 16 q-rows x 128 B (swizzled)

  const int lin = blockIdx.x;
  const int g   = lin & 7;            // kv head == XCD hint
  const int rr  = lin >> 3;           // 0..95
  const int hg  = rr % 6;
  const int pr  = rr / 6;             // 0..15
  const int h   = g * 6 + hg;
  const int tid = threadIdx.x, wave = tid >> 6, lane = tid & 63;
  const int lr = lane & 15, lk = (lane >> 4) * 8, li4 = (lane >> 4) * 4;
  const unsigned short* Qh = Q + (size_t)h * (TSEQ * HDIM);
  const unsigned char*  Kb = (const unsigned char*)(K + (size_t)g * (TSEQ * HDIM));
  const unsigned char*  Vb = (const unsigned char*)(V + (size_t)g * (TSEQ * HDIM));
  unsigned char* Pw = PsB[wave];

  for (int half = 0; half < 2; ++half) {
    const int j  = half ? (31 - pr) : pr;     // q-tile index (64 rows)
    const int t0 = j * 64 + wave * 16;        // this wave's 16 rows
    const int nst = j + 1;

    short8 qf[4];
#pragma unroll
    for (int ks = 0; ks < 4; ++ks)
      qf[ks] = *(const short8*)(Qh + (size_t)(t0 + lr) * HDIM + ks * 32 + lk);

    f32x4 oacc[8];
#pragma unroll
    for (int n = 0; n < 8; ++n) oacc[n] = (f32x4){0.f, 0.f, 0.f, 0.f};
    float rs4[4] = {0.f, 0.f, 0.f, 0.f};

    for (int st = 0; st < nst; ++st) {
      const int s0 = st * 64;
#pragma unroll
      for (int c = 0; c < 4; ++c) {
        const int FF = tid * 16 + c * 4096;
        const int krow = FF >> 8;
        const int kcol = (FF & 255) ^ ((krow & 7) << 4);
        gload_lds16(Kb + (size_t)(s0 + krow) * 256 + kcol, KsB + FF);
        const int vrow = FF >> 7;
        const int vcol = (FF & 127) ^ ((vrow & 7) << 4);
        gload_lds16(Vb + (size_t)vrow * (TSEQ * 2) + (size_t)s0 * 2 + vcol, VsB + FF);
      }
      __syncthreads();

      f32x4 sacc[4];
#pragma unroll
      for (int n = 0; n < 4; ++n) sacc[n] = (f32x4){0.f, 0.f, 0.f, 0.f};
#pragma unroll
      for (int ks = 0; ks < 4; ++ks) {
        short8 kf[4];
#pragma unroll
        for (int n = 0; n < 4; ++n) {
          const int row = n * 16 + lr;
          kf[n] = *(const short8*)(KsB + row * 256 + ((ks * 64 + lk * 2) ^ ((row & 7) << 4)));
        }
#pragma unroll
        for (int n = 0; n < 4; ++n)
          sacc[n] = __builtin_amdgcn_mfma_f32_16x16x32_bf16(qf[ks], kf[n], sacc[n], 0, 0, 0);
      }

      const bool lastst = (st == nst - 1);
#pragma unroll
      for (int n = 0; n < 4; ++n)
#pragma unroll
        for (int i = 0; i < 4; ++i) {
          float sv = sacc[n][i] * 0.08838834764831845f;   // 1/sqrt(128)
          float e = EXP2(sv * 0.09617966939259757f);       // e^(s/15)
          float p = EXP2(-86.5617024533378f * RCP(e + 1.0f));
          if (lastst && (s0 + n * 16 + lr > t0 + li4 + i)) p = 0.f;
          rs4[i] += p;
          const int prow = li4 + i;
          *(unsigned short*)(Pw + prow * 128 +
              (((n * 16 + lr) * 2) ^ ((prow & 7) << 4))) = f2b(p);
        }

#pragma unroll
      for (int ks2 = 0; ks2 < 2; ++ks2) {
        short8 pf = *(const short8*)(Pw + lr * 128 +
                         (((ks2 * 32 + lk) * 2) ^ ((lr & 7) << 4)));
        short8 vf[8];
#pragma unroll
        for (int n = 0; n < 8; ++n) {
          const int row = n * 16 + lr;
          vf[n] = *(const short8*)(VsB + row * 128 + ((ks2 * 64 + lk * 2) ^ ((row & 7) << 4)));
        }
#pragma unroll
        for (int n = 0; n < 8; ++n)
          oacc[n] = __builtin_amdgcn_mfma_f32_16x16x32_bf16(pf, vf[n], oacc[n], 0, 0, 0);
      }
      __syncthreads();
    }

    float inv4[4];
#pragma unroll
    for (int i = 0; i < 4; ++i) {
      float v = rs4[i];
      v += __shfl_xor(v, 1, 64);
      v += __shfl_xor(v, 2, 64);
      v += __shfl_xor(v, 4, 64);
      v += __shfl_xor(v, 8, 64);
      inv4[i] = RCP(v);
    }
#pragma unroll
    for (int n = 0; n < 8; ++n)
#pragma unroll
      for (int i = 0; i < 4; ++i)
        O[(size_t)(t0 + li4 + i) * DMODEL + h * HDIM + n * 16 + lr] =
            f2b(oacc[n][i] * inv4[i]);
  }
}

// ---------- launch ----------

extern "C" void kernel_launch(void* const* d_in, const int* in_sizes, int n_in,
                              void* d_out, int out_size, void* d_ws, size_t ws_size,
                              hipStream_t stream) {
  const int*   pos  = (const int*)d_in[0];
  const float* hid  = (const float*)d_in[1];
  const float* wqkv = (const float*)d_in[2];
  const float* wo   = (const float*)d_in[3];
  float* out = (float*)d_out;
  char* ws = (char*)d_ws;

  const size_t O_XB   = 0;                         // Xb bf16 [2048][6144]; later attn_out
  const size_t O_WQT  = 25165824;                  // Wqkv^T bf16 [8192][6144]; later Q/K/Vt
  const size_t O_WOT  = 125829120;                 // Wo^T bf16 [6144][6144]
  const size_t O_QKV  = 201326592;                 // QKV bf16 [2048][8192]
  const size_t O_TRIG = 268435456;                 // cos/sin f32 [2048][64] each

  unsigned short* Xb  = (unsigned short*)(ws + O_XB);
  unsigned short* Wqt = (unsigned short*)(ws + O_WQT);
  unsigned short* Wot = (unsigned short*)(ws + O_WOT);
  unsigned short* QKVb = (unsigned short*)(ws + O_QKV);
  float* CS  = (float*)(ws + O_TRIG);
  float* SN  = CS + TSEQ * 64;
  unsigned short* Qr = Wqt;                                  // [48][2048][128]
  unsigned short* Kr = Wqt + (size_t)NHEADS * TSEQ * HDIM;   // [8][2048][128]
  unsigned short* Vt = Kr + (size_t)NKVH * TSEQ * HDIM;      // [8][128][2048]
  unsigned short* AO = Xb;                                   // attn_out bf16 [2048][6144]

  hipFuncSetAttribute((const void*)k_gemm8<unsigned short>,
                      hipFuncAttributeMaxDynamicSharedMemorySize, 131072);
  hipFuncSetAttribute((const void*)k_gemm8<float>,
                      hipFuncAttributeMaxDynamicSharedMemorySize, 131072);

  k_cvt<<<(TSEQ * DMODEL) / (256 * 8), 256, 0, stream>>>(hid, Xb, TSEQ * DMODEL);
  // Wqkv^T: in 6144x8192 -> out 8192x6144
  k_tr2<<<dim3(QKVC / 64, DMODEL / 64, 1), 256, 0, stream>>>(wqkv, QKVC, 0, Wqt, DMODEL, 0);
  // Wo^T: in 6144x6144 -> out 6144x6144
  k_tr2<<<dim3(DMODEL / 64, DMODEL / 64, 1), 256, 0, stream>>>(wo, DMODEL, 0, Wot, DMODEL, 0);
  k_trig<<<TSEQ, 64, 0, stream>>>(pos, CS, SN);

  k_gemm8<unsigned short><<<(TSEQ / 256) * (QKVC / 256), 512, 131072, stream>>>(
      Xb, Wqt, QKVb, TSEQ, QKVC, DMODEL);
  k_rope<<<TSEQ, 256, 0, stream>>>(QKVb, CS, SN, Qr, Kr);
  // Vt: per head z, in QKVb[t][7168 + z*128 + d] (2048x128 bf16) -> Vt[z][d][t]
  k_tr2b<<<dim3(HDIM / 64, TSEQ / 64, NKVH), 256, 0, stream>>>(
      QKVb + (size_t)(DMODEL + NKVH * HDIM), QKVC, HDIM,
      Vt, TSEQ, (size_t)HDIM * TSEQ);
  k_attn2<<<768, 256, 0, stream>>>(Qr, Kr, Vt, AO);
  k_gemm8<float><<<(TSEQ / 256) * (DMODEL / 256), 512, 131072, stream>>>(
      AO, Wot, out, TSEQ, DMODEL, DMODEL);
}